// Round 13
// baseline (1227.055 us; speedup 1.0000x reference)
//
#include <hip/hip_runtime.h>

#define T_SEQ 2048
#define NB    2
#define NH    32
#define NKV   8
#define HD    128
#define DIM   4096
#define EDIM  6144
#define M_TOK 4096   // NB*T_SEQ

typedef __bf16          bf8  __attribute__((ext_vector_type(8)));
typedef unsigned short  us8  __attribute__((ext_vector_type(8)));
typedef float           f4   __attribute__((ext_vector_type(4)));
typedef float           f16v __attribute__((ext_vector_type(16)));
typedef int             i4   __attribute__((ext_vector_type(4)));

__device__ inline unsigned short f2bf(float f) {
  unsigned int u = __builtin_bit_cast(unsigned int, f);
  u += 0x7FFF + ((u >> 16) & 1);              // round-to-nearest-even
  return (unsigned short)(u >> 16);
}
__device__ inline float bf2f(unsigned short h) {
  unsigned int u = ((unsigned int)h) << 16;
  return __builtin_bit_cast(float, u);
}
__device__ inline void gl_lds16(const void* g, void* l) {
  __builtin_amdgcn_global_load_lds(
      (const __attribute__((address_space(1))) unsigned int*)g,
      (__attribute__((address_space(3))) unsigned int*)l, 16, 0, 0);
}
__device__ inline f4 mfma16(bf8 a, bf8 b, f4 c) {
  return __builtin_amdgcn_mfma_f32_16x16x32_bf16(a, b, c, 0, 0, 0);
}
__device__ inline f16v mfma32(bf8 a, bf8 b, f16v c) {
  return __builtin_amdgcn_mfma_f32_32x32x16_bf16(a, b, c, 0, 0, 0);
}
__device__ inline unsigned cvtpk(float lo, float hi) {
  unsigned r;
  asm("v_cvt_pk_bf16_f32 %0, %1, %2" : "=v"(r) : "v"(lo), "v"(hi));
  return r;
}

// ---------------- fused f32 -> bf16 conversion (x, wqkv, wo in one launch) ----------------
__global__ void k_f2bf3(const float* __restrict__ x, const float* __restrict__ wq,
                        const float* __restrict__ wo,
                        unsigned short* __restrict__ xb, unsigned short* __restrict__ wqb,
                        unsigned short* __restrict__ wob) {
  const long n0 = (long)M_TOK * DIM / 4;
  const long n1 = (long)EDIM * DIM / 4;
  const long n2 = (long)DIM * DIM / 4;
  const long total = n0 + n1 + n2;
  const long stride = (long)gridDim.x * blockDim.x;
  for (long i = (long)blockIdx.x * blockDim.x + threadIdx.x; i < total; i += stride) {
    const float* in; unsigned short* out; long j = i;
    if (j < n0)              { in = x;  out = xb; }
    else if ((j -= n0) < n1) { in = wq; out = wqb; }
    else       { j -= n1;      in = wo; out = wob; }
    f4 v = *(const f4*)(in + j * 4);
    unsigned long long pack =
        (unsigned long long)f2bf(v[0]) |
        ((unsigned long long)f2bf(v[1]) << 16) |
        ((unsigned long long)f2bf(v[2]) << 32) |
        ((unsigned long long)f2bf(v[3]) << 48);
    *(unsigned long long*)(out + j * 4) = pack;
  }
}

// =============== GEMM1: 128x384 tiles, 3-phase, SINGLE-BUFFERED LDS (64 KiB) ===============
// R13: panels die right after their phase's lgkm0+barrier (A/B0 at ph1-end -- frags
// live in regs; B1 at ph2-end; B2 at ph3-end), so next-tile stages reuse the SAME
// slots: ph1 stages B2(tc), ph2 stages A,B0(tc+1), ph3 stages B1(tc+1).
// 64 KiB LDS -> 2 blocks/CU = 4 waves/SIMD; grid 512 = one fully-resident round.
// Publish ledger: prologue[A,B0,B1(0)] vmcnt(2); ph1-end vmcnt(2) [B1(tc)];
// ph2-end vmcnt(4) [B2(tc)]; ph3-end vmcnt(2) [A,B0(tc+1)].
// Last tile: ph2-end vmcnt(0) (stages skipped), ph3 no trailing wait.
__global__ __launch_bounds__(512, 4)
void k_gemm384(const unsigned short* __restrict__ A, const unsigned short* __restrict__ Bm,
               unsigned short* __restrict__ oQ, unsigned short* __restrict__ oK,
               unsigned short* __restrict__ oV) {
  __shared__ unsigned short As[8192];
  __shared__ unsigned short Bs[3][8192];
  const int n0 = blockIdx.x;
  const int x = n0 & 7, ix = n0 >> 3;          // ix in [0,64)
  const int bm = ((x >> 1) << 3) + (ix >> 3);  // [0,32)
  const int bn = ((x & 1) << 3) + (ix & 7);    // [0,16)
  const int t = threadIdx.x;
  const int lane = t & 63, w = t >> 6;
  const int wr = w >> 2, wc = w & 3;
  const int l15 = lane & 15, lhi = lane >> 4;
  const int KT = DIM >> 6;                     // 64

  f4 acc[4][6] = {};                           // [mi][bh*2+ni]

  const int tt0 = t * 8;
  auto stA = [&](int tile) {
    if (tile >= KT) return;
    const unsigned short* gp = A + (size_t)(bm * 128) * DIM + tile * 64;
#pragma unroll
    for (int j = 0; j < 2; ++j) {
      int e = j * 4096 + tt0;
      int rl = e >> 6, cs = (e & 63) ^ ((rl & 7) << 3);
      gl_lds16(gp + (size_t)rl * DIM + cs, &As[e]);
    }
  };
  auto stB = [&](int bh, int tile) {
    if (tile >= KT) return;
    const unsigned short* gp = Bm + (size_t)(bn * 384 + bh * 128) * DIM + tile * 64;
#pragma unroll
    for (int j = 0; j < 2; ++j) {
      int e = j * 4096 + tt0;
      int rl = e >> 6, cs = (e & 63) ^ ((rl & 7) << 3);
      gl_lds16(gp + (size_t)rl * DIM + cs, &Bs[bh][e]);
    }
  };
  auto rdA = [&](int mi, int kk) -> bf8 {
    int row = wr * 64 + mi * 16 + l15;
    int col = (lhi * 8 + kk * 32) ^ ((row & 7) << 3);
    return __builtin_bit_cast(bf8, *(const us8*)&As[row * 64 + col]);
  };
  auto rdB = [&](int bh, int ni, int kk) -> bf8 {
    int row = wc * 32 + ni * 16 + l15;
    int col = (lhi * 8 + kk * 32) ^ ((row & 7) << 3);
    return __builtin_bit_cast(bf8, *(const us8*)&Bs[bh][row * 64 + col]);
  };
  auto bar = [&]() {
    asm volatile("" ::: "memory");
    __builtin_amdgcn_s_barrier();
    asm volatile("" ::: "memory");
  };
  auto lgkm0 = [&]() {
    asm volatile("s_waitcnt lgkmcnt(0)" ::: "memory");
    __builtin_amdgcn_sched_barrier(0);
  };

  // prologue: stage A,B0,B1 of tile0 (6 loads); publish A,B0 (leave B1 in flight)
  stA(0); stB(0, 0); stB(1, 0);
  asm volatile("s_waitcnt vmcnt(2)" ::: "memory");
  bar();

  for (int tc = 0; tc < KT; ++tc) {
    const bool last = (tc == KT - 1);
    bf8 af[4][2], bfr[2][2];
    // ---- ph1: stage B2(tc); read A,B0(tc); MFMA b0 ----
    stB(2, tc);
#pragma unroll
    for (int mi = 0; mi < 4; ++mi)
#pragma unroll
      for (int kk = 0; kk < 2; ++kk) af[mi][kk] = rdA(mi, kk);
#pragma unroll
    for (int ni = 0; ni < 2; ++ni)
#pragma unroll
      for (int kk = 0; kk < 2; ++kk) bfr[ni][kk] = rdB(0, ni, kk);
    lgkm0();
    __builtin_amdgcn_s_setprio(1);
#pragma unroll
    for (int mi = 0; mi < 4; ++mi)
#pragma unroll
      for (int ni = 0; ni < 2; ++ni)
#pragma unroll
        for (int kk = 0; kk < 2; ++kk)
          acc[mi][ni] = mfma16(af[mi][kk], bfr[ni][kk], acc[mi][ni]);
    __builtin_amdgcn_s_setprio(0);
    asm volatile("s_waitcnt vmcnt(2)" ::: "memory");   // publish B1(tc)
    bar();
    // ---- ph2: stage A,B0(tc+1); read B1(tc); MFMA b1 ----
    stA(tc + 1); stB(0, tc + 1);
#pragma unroll
    for (int ni = 0; ni < 2; ++ni)
#pragma unroll
      for (int kk = 0; kk < 2; ++kk) bfr[ni][kk] = rdB(1, ni, kk);
    lgkm0();
    __builtin_amdgcn_s_setprio(1);
#pragma unroll
    for (int mi = 0; mi < 4; ++mi)
#pragma unroll
      for (int ni = 0; ni < 2; ++ni)
#pragma unroll
        for (int kk = 0; kk < 2; ++kk)
          acc[mi][2 + ni] = mfma16(af[mi][kk], bfr[ni][kk], acc[mi][2 + ni]);
    __builtin_amdgcn_s_setprio(0);
    if (last) { asm volatile("s_waitcnt vmcnt(0)" ::: "memory"); }
    else      { asm volatile("s_waitcnt vmcnt(4)" ::: "memory"); }   // publish B2(tc)
    bar();
    // ---- ph3: stage B1(tc+1); read B2(tc); MFMA b2 ----
    stB(1, tc + 1);
#pragma unroll
    for (int ni = 0; ni < 2; ++ni)
#pragma unroll
      for (int kk = 0; kk < 2; ++kk) bfr[ni][kk] = rdB(2, ni, kk);
    lgkm0();
    __builtin_amdgcn_s_setprio(1);
#pragma unroll
    for (int mi = 0; mi < 4; ++mi)
#pragma unroll
      for (int ni = 0; ni < 2; ++ni)
#pragma unroll
        for (int kk = 0; kk < 2; ++kk)
          acc[mi][4 + ni] = mfma16(af[mi][kk], bfr[ni][kk], acc[mi][4 + ni]);
    __builtin_amdgcn_s_setprio(0);
    if (!last) {
      asm volatile("s_waitcnt vmcnt(2)" ::: "memory");  // publish A,B0(tc+1)
      bar();
    }
  }

  // epilogue: Q/K/V region per 16-col sub-block (boundaries 4096/5120 are x16)
#pragma unroll
  for (int bh = 0; bh < 3; ++bh)
#pragma unroll
    for (int ni = 0; ni < 2; ++ni) {
      const int colb = bn * 384 + bh * 128 + wc * 32 + ni * 16;
      unsigned short* op; int ldo, c0;
      if (colb < 4096)      { op = oQ; ldo = 4096; c0 = colb; }
      else if (colb < 5120) { op = oK; ldo = 1024; c0 = colb - 4096; }
      else                  { op = oV; ldo = 1024; c0 = colb - 5120; }
#pragma unroll
      for (int mi = 0; mi < 4; ++mi)
#pragma unroll
        for (int rr = 0; rr < 4; ++rr) {
          int row = bm * 128 + wr * 64 + mi * 16 + lhi * 4 + rr;
          op[(size_t)row * ldo + c0 + l15] = f2bf(acc[mi][bh * 2 + ni][rr]);
        }
    }
}

// =============== GEMM2: 256x256 8-phase mfma16, f32 out; single barrier/phase ======
#define MFMA_Q(a0, b0, AF, BF)                                        \
  __builtin_amdgcn_s_setprio(1);                                      \
  _Pragma("unroll") for (int mi = 0; mi < 4; ++mi)                    \
  _Pragma("unroll") for (int ni = 0; ni < 2; ++ni)                    \
  _Pragma("unroll") for (int kk = 0; kk < 2; ++kk)                    \
      acc[(a0) + mi][(b0) + ni] =                                     \
          mfma16(AF[mi][kk], BF[ni][kk], acc[(a0) + mi][(b0) + ni]);  \
  __builtin_amdgcn_s_setprio(0);

#define RD_A(buf, mh)                                                 \
  _Pragma("unroll") for (int mi = 0; mi < 4; ++mi)                    \
  _Pragma("unroll") for (int kk = 0; kk < 2; ++kk)                    \
      af[mi][kk] = rdA(buf, mh, mi, kk);

#define RD_B(buf, nh, BF)                                             \
  _Pragma("unroll") for (int ni = 0; ni < 2; ++ni)                    \
  _Pragma("unroll") for (int kk = 0; kk < 2; ++kk)                    \
      BF[ni][kk] = rdB(buf, nh, ni, kk);

__global__ __launch_bounds__(512, 2)
void k_gemm256f(const unsigned short* __restrict__ A, const unsigned short* __restrict__ Bm,
                float* __restrict__ oF) {
  __shared__ unsigned short As[2][16384];
  __shared__ unsigned short Bs[2][16384];
  // grid 256 = 16bm x 16bn; XCD x owns a 4bm x 8bn chunk (bn fast)
  const int n0 = blockIdx.x;
  const int x = n0 & 7, ix = n0 >> 3;          // ix in [0,32)
  const int bm = ((x >> 1) << 2) + (ix >> 3);  // [0,16)
  const int bn = ((x & 1) << 3) + (ix & 7);    // [0,16)
  const int N = DIM, K = DIM;
  const int t = threadIdx.x;
  const int lane = t & 63, w = t >> 6;
  const int wr = w >> 2, wc = w & 3;
  const int l15 = lane & 15, lhi = lane >> 4;
  const int KT = K >> 6;
  const int NI = KT >> 1;

  f4 acc[8][4] = {};

  const int tt0 = t * 8;
  auto stA = [&](int buf, int half, int tile) {
    if (tile >= KT) return;
    const unsigned short* gp = A + (size_t)(bm * 256 + half * 128) * K + tile * 64;
#pragma unroll
    for (int j = 0; j < 2; ++j) {
      int e = j * 4096 + tt0;
      int rl = e >> 6;
      int cs = (e & 63) ^ ((rl & 7) << 3);
      gl_lds16(gp + (size_t)rl * K + cs, &As[buf][half * 8192 + e]);
    }
  };
  auto stB = [&](int buf, int half, int tile) {
    if (tile >= KT) return;
    const unsigned short* gp = Bm + (size_t)(bn * 256 + half * 128) * K + tile * 64;
#pragma unroll
    for (int j = 0; j < 2; ++j) {
      int e = j * 4096 + tt0;
      int rl = e >> 6;
      int cs = (e & 63) ^ ((rl & 7) << 3);
      gl_lds16(gp + (size_t)rl * K + cs, &Bs[buf][half * 8192 + e]);
    }
  };
  auto rdA = [&](int buf, int mh, int mi, int kk) -> bf8 {
    int row = mh * 128 + wr * 64 + mi * 16 + l15;
    int col = (lhi * 8 + kk * 32) ^ ((row & 7) << 3);
    return __builtin_bit_cast(bf8, *(const us8*)&As[buf][row * 64 + col]);
  };
  auto rdB = [&](int buf, int nh, int ni, int kk) -> bf8 {
    int row = nh * 128 + wc * 32 + ni * 16 + l15;
    int col = (lhi * 8 + kk * 32) ^ ((row & 7) << 3);
    return __builtin_bit_cast(bf8, *(const us8*)&Bs[buf][row * 64 + col]);
  };
  auto bar = [&]() {
    asm volatile("" ::: "memory");
    __builtin_amdgcn_s_barrier();
    asm volatile("" ::: "memory");
  };
  auto lgkm0 = [&]() {
    asm volatile("s_waitcnt lgkmcnt(0)" ::: "memory");
    __builtin_amdgcn_sched_barrier(0);
  };

  stA(0, 0, 0); stB(0, 1, 0); stA(0, 1, 0); stB(0, 0, 0);
  stA(1, 0, 1); stB(1, 1, 1); stA(1, 1, 1);
  asm volatile("s_waitcnt vmcnt(6)" ::: "memory");
  bar();

  for (int i = 0; i < NI; ++i) {
    const int t2 = 2 * i + 2, t3 = 2 * i + 3;
    bf8 af[4][2], bf0[2][2], bf1[2][2];
    // ph1
    RD_A(0, 0); RD_B(0, 0, bf0);
    stB(1, 0, 2 * i + 1);
    lgkm0();
    MFMA_Q(0, 0, af, bf0);
    bar();
    // ph2
    RD_B(0, 1, bf1);
    stA(0, 0, t2);
    lgkm0();
    MFMA_Q(0, 2, af, bf1);
    bar();
    // ph3
    RD_A(0, 1);
    stB(0, 1, t2);
    lgkm0();
    MFMA_Q(4, 2, af, bf1);
    bar();
    // ph4 (bf0 retained from ph1 - no re-read)
    stA(0, 1, t2);
    MFMA_Q(4, 0, af, bf0);
    if (i + 1 < NI) { asm volatile("s_waitcnt vmcnt(6)" ::: "memory"); }
    else            { asm volatile("s_waitcnt vmcnt(0)" ::: "memory"); }
    bar();
    // ph5
    RD_A(1, 0); RD_B(1, 0, bf0);
    stB(0, 0, t2);
    lgkm0();
    MFMA_Q(0, 0, af, bf0);
    bar();
    // ph6
    RD_B(1, 1, bf1);
    stA(1, 0, t3);
    lgkm0();
    MFMA_Q(0, 2, af, bf1);
    bar();
    // ph7
    RD_A(1, 1);
    stB(1, 1, t3);
    lgkm0();
    MFMA_Q(4, 2, af, bf1);
    bar();
    // ph8 (bf0 retained from ph5)
    stA(1, 1, t3);
    MFMA_Q(4, 0, af, bf0);
    if (i + 1 < NI) { asm volatile("s_waitcnt vmcnt(6)" ::: "memory"); }
    bar();
  }

  const int rb0 = bm * 256 + wr * 64 + lhi * 4;
  const int cb0 = bn * 256 + wc * 32 + l15;
#pragma unroll
  for (int ai = 0; ai < 8; ++ai)
#pragma unroll
    for (int bj = 0; bj < 4; ++bj)
#pragma unroll
      for (int rr = 0; rr < 4; ++rr) {
        int row = rb0 + (ai >> 2) * 128 + (ai & 3) * 16 + rr;
        int col = cb0 + (bj >> 1) * 128 + (bj & 1) * 16;
        oF[(size_t)row * N + col] = acc[ai][bj][rr];
      }
}

// ---------------- Flash attention, BALANCED pairs (R12 version) ----------------
__global__ __launch_bounds__(512, 2)
void k_attn(const unsigned short* __restrict__ Qb, const unsigned short* __restrict__ Kb,
            const unsigned short* __restrict__ Vb, unsigned short* __restrict__ Yb,
            const float* __restrict__ cosp, const float* __restrict__ sinp) {
  __shared__ unsigned short Ks[64 * 128];
  __shared__ unsigned short Vt[128 * 64];
  const int idx = blockIdx.x;               // [0,256)
  const int p = idx >> 6;                   // pair index [0,4)
  const int hb = idx & 63;
  const int h = hb >> 1;
  const int b = hb & 1;
  const int kvh = h >> 2;
  const int t = threadIdx.x;
  const int lane = t & 63, w = t >> 6;
  const int l31 = lane & 31, hh = lane >> 5;
  const float BNEG = -1.0e30f;
  const float QSCALE = (float)(0.08838834764831845 * 1.4426950408889634);
  const int swz = (l31 & 7) << 3;           // element-unit XOR swizzle (bits 3..5)
  const int krow = t >> 4;                  // [0,32): K staging row (i=0), +32 (i=1)
  const int kcol = (t & 15) * 8;            // 4 interleaved pairs, 8 contiguous elems

  for (int qq = 0; qq < 2; ++qq) {
    const int qblk = qq ? p : 7 - p;        // heavy tile first
    const int qb0 = qblk * 256;
    const int NT = (qblk + 1) * 4;
    const int wqmin = qb0 + w * 32;
    const int q_g = wqmin + l31;            // this lane's q row (S/P layout)

    // Q fragments, roped in-register
    bf8 qf[8];
    {
      const unsigned short* qp = Qb + (size_t)(b * T_SEQ + q_g) * 4096 + h * 128 + hh * 8;
#pragma unroll
      for (int st = 0; st < 8; ++st) {
        us8 v = *(const us8*)(qp + st * 16);
        f4 c = *(const f4*)(cosp + q_g * 64 + st * 8 + hh * 4);
        f4 s = *(const f4*)(sinp + q_g * 64 + st * 8 + hh * 4);
        us8 o;
#pragma unroll
        for (int j = 0; j < 4; ++j) {
          float tr = bf2f(v[2 * j]), ti = bf2f(v[2 * j + 1]);
          o[2 * j]     = f2bf((tr * c[j] - ti * s[j]) * QSCALE);
          o[2 * j + 1] = f2bf((tr * s[j] + ti * c[j]) * QSCALE);
        }
        qf[st] = __builtin_bit_cast(bf8, o);
      }
    }
    float m_run = BNEG, l_run = 0.f;
    f16v yacc[4] = {};

    for (int kt = 0; kt < NT; ++kt) {
      const int kbase = kt * 64;
      // hoisted global loads (V and K), land during barrier wait
      const unsigned short* vp = Vb + (size_t)(b * T_SEQ + kbase + lane) * 1024 + kvh * 128 + w * 8;
      us8 vv0 = *(const us8*)vp;
      us8 vv1 = *(const us8*)(vp + 64);
      const unsigned short* kp = Kb + (size_t)(b * T_SEQ + kbase + krow) * 1024 + kvh * 128 + kcol;
      us8 kk0 = *(const us8*)kp;
      us8 kk1 = *(const us8*)(kp + (size_t)32 * 1024);
      f4 kc0 = *(const f4*)(cosp + (kbase + krow) * 64 + (kcol >> 1));
      f4 ks0 = *(const f4*)(sinp + (kbase + krow) * 64 + (kcol >> 1));
      f4 kc1 = *(const f4*)(cosp + (kbase + krow + 32) * 64 + (kcol >> 1));
      f4 ks1 = *(const f4*)(sinp + (kbase + krow + 32) * 64 + (kcol >> 1));
      __syncthreads();                      // prev tile's LDS reads done
      // K: rope in-register, write to swizzled LDS
      {
        us8 o0, o1;
#pragma unroll
        for (int j = 0; j < 4; ++j) {
          float tr0 = bf2f(kk0[2 * j]), ti0 = bf2f(kk0[2 * j + 1]);
          o0[2 * j]     = f2bf(tr0 * kc0[j] - ti0 * ks0[j]);
          o0[2 * j + 1] = f2bf(tr0 * ks0[j] + ti0 * kc0[j]);
          float tr1 = bf2f(kk1[2 * j]), ti1 = bf2f(kk1[2 * j + 1]);
          o1[2 * j]     = f2bf(tr1 * kc1[j] - ti1 * ks1[j]);
          o1[2 * j + 1] = f2bf(tr1 * ks1[j] + ti1 * kc1[j]);
        }
        *(us8*)&Ks[krow * 128 + (kcol ^ ((krow & 7) << 3))] = o0;
        *(us8*)&Ks[(krow + 32) * 128 + (kcol ^ ((krow & 7) << 3))] = o1;
      }
      // V: transpose-scatter into swizzled Vt
#pragma unroll
      for (int j = 0; j < 8; ++j) {
        int d0 = w * 8 + j;
        Vt[(d0 * 64 + lane) ^ ((d0 & 7) << 3)] = vv0[j];
        int d1 = d0 + 64;
        Vt[(d1 * 64 + lane) ^ ((d1 & 7) << 3)] = vv1[j];
      }
      __syncthreads();                      // staged data visible
      if (kbase > wqmin + 31) continue;     // tile fully masked for this wave (uniform)

      f16v s0 = {}, s1 = {};
#pragma unroll
      for (int st = 0; st < 8; ++st) {
        int coff = st * 16 + hh * 8;
        bf8 a0 = __builtin_bit_cast(bf8, *(const us8*)&Ks[(l31 * 128 + coff) ^ swz]);
        bf8 a1 = __builtin_bit_cast(bf8, *(const us8*)&Ks[((l31 + 32) * 128 + coff) ^ swz]);
        s0 = mfma32(a0, qf[st], s0);
        s1 = mfma32(a1, qf[st], s1);
      }
      if (kbase + 63 > wqmin) {
#pragma unroll
        for (int r = 0; r < 16; ++r) {
          int kv = kbase + (r & 3) + 8 * (r >> 2) + 4 * hh;
          if (kv > q_g)      s0[r] = BNEG;
          if (kv + 32 > q_g) s1[r] = BNEG;
        }
      }
      float tmax = BNEG;
#pragma unroll
      for (int r = 0; r < 16; ++r) {
        tmax = fmaxf(tmax, s0[r]);
        tmax = fmaxf(tmax, s1[r]);
      }
      tmax = fmaxf(tmax, __shfl_xor(tmax, 32));
      float m_new = fmaxf(m_run, tmax);
      float fac = exp2f(m_run - m_new);     // per q=l31; exact 1.0 when max unchanged
      m_run = m_new;
      float psum = 0.f;
#pragma unroll
      for (int r = 0; r < 16; ++r) {
        s0[r] = exp2f(s0[r] - m_new); psum += s0[r];
        s1[r] = exp2f(s1[r] - m_new); psum += s1[r];
      }
      psum += __shfl_xor(psum, 32);
      l_run = l_run * fac + psum;
      if (!__all(fac == 1.0f)) {
        float facr[16];
#pragma unroll
        for (int r = 0; r < 16; ++r)
          facr[r] = __shfl(fac, (r & 3) + 8 * (r >> 2) + 4 * hh);
#pragma unroll
        for (int dc = 0; dc < 4; ++dc)
#pragma unroll
          for (int r = 0; r < 16; ++r) yacc[dc][r] *= facr[r];
      }
#pragma unroll
      for (int st = 0; st < 4; ++st) {
        f16v sv = (st & 2) ? s1 : s0;
        const int rb = (st & 1) * 8;
        unsigned pkA = cvtpk(sv[rb + 0], sv[rb + 1]);
        unsigned pkB = cvtpk(sv[rb + 2], sv[rb + 3]);
        unsigned pkC = cvtpk(sv[rb + 4], sv[rb + 5]);
        unsigned pkD = cvtpk(sv[rb + 6], sv[rb + 7]);
        unsigned xA = __shfl_xor(pkA, 32);
        unsigned xB = __shfl_xor(pkB, 32);
        unsigned xC = __shfl_xor(pkC, 32);
        unsigned xD = __shfl_xor(pkD, 32);
        unsigned w0 = hh ? xC : pkA;
        unsigned w1 = hh ? xD : pkB;
        unsigned w2 = hh ? pkC : xA;
        unsigned w3 = hh ? pkD : xB;
        i4 wi = { (int)w0, (int)w1, (int)w2, (int)w3 };
        bf8 pf = __builtin_bit_cast(bf8, wi);
#pragma unroll
        for (int dc = 0; dc < 4; ++dc) {
          int d = dc * 32 + l31;
          bf8 vf = __builtin_bit_cast(bf8, *(const us8*)&Vt[(d * 64 + st * 16 + hh * 8) ^ swz]);
          yacc[dc] = mfma32(pf, vf, yacc[dc]);
        }
      }
    }
    float inv_l = 1.0f / l_run;
    float il[16];
#pragma unroll
    for (int r = 0; r < 16; ++r)
      il[r] = __shfl(inv_l, (r & 3) + 8 * (r >> 2) + 4 * hh);
#pragma unroll
    for (int dc = 0; dc < 4; ++dc)
#pragma unroll
      for (int r = 0; r < 16; ++r) {
        int qrow = qb0 + w * 32 + (r & 3) + 8 * (r >> 2) + 4 * hh;
        Yb[(size_t)(b * T_SEQ + qrow) * 4096 + h * 128 + dc * 32 + l31] =
            f2bf(yacc[dc][r] * il[r]);
      }
  }
}

extern "C" void kernel_launch(void* const* d_in, const int* in_sizes, int n_in,
                              void* d_out, int out_size, void* d_ws, size_t ws_size,
                              hipStream_t stream) {
  const float* x    = (const float*)d_in[0];
  // d_in[1] = freqs_cis (unused by the reference computation)
  const float* wqkv = (const float*)d_in[2];
  const float* wo   = (const float*)d_in[3];
  const float* cosp = (const float*)d_in[4];
  const float* sinp = (const float*)d_in[5];
  float* out = (float*)d_out;

  char* ws = (char*)d_ws;
  size_t o = 0;
  auto alloc = [&](size_t bytes) { void* p = ws + o; o += (bytes + 255) & ~(size_t)255; return p; };
  unsigned short* x_b    = (unsigned short*)alloc((size_t)M_TOK * DIM * 2);
  unsigned short* wqkv_b = (unsigned short*)alloc((size_t)EDIM * DIM * 2);
  unsigned short* wo_b   = (unsigned short*)alloc((size_t)DIM * DIM * 2);
  unsigned short* Qb     = (unsigned short*)alloc((size_t)M_TOK * 4096 * 2);
  unsigned short* Kb     = (unsigned short*)alloc((size_t)M_TOK * 1024 * 2);
  unsigned short* Vb     = (unsigned short*)alloc((size_t)M_TOK * 1024 * 2);
  unsigned short* Yb     = (unsigned short*)alloc((size_t)M_TOK * 4096 * 2);
  if (o > ws_size) return;  // workspace too small: fail visibly (zero output)

  k_f2bf3<<<2048, 256, 0, stream>>>(x, wqkv, wo, x_b, wqkv_b, wo_b);

  k_gemm384<<<dim3(512), 512, 0, stream>>>(x_b, wqkv_b, Qb, Kb, Vb);

  k_attn<<<dim3(256, 1, 1), 512, 0, stream>>>(Qb, Kb, Vb, Yb, cosp, sinp);

  k_gemm256f<<<dim3(256), 512, 0, stream>>>(Yb, wo_b, out);
}

// Round 14
// 521.834 us; speedup vs baseline: 2.3514x; 2.3514x over previous
//
#include <hip/hip_runtime.h>

#define T_SEQ 2048
#define NB    2
#define NH    32
#define NKV   8
#define HD    128
#define DIM   4096
#define EDIM  6144
#define M_TOK 4096   // NB*T_SEQ

typedef __bf16          bf8  __attribute__((ext_vector_type(8)));
typedef unsigned short  us8  __attribute__((ext_vector_type(8)));
typedef float           f4   __attribute__((ext_vector_type(4)));
typedef float           f16v __attribute__((ext_vector_type(16)));
typedef int             i4   __attribute__((ext_vector_type(4)));

__device__ inline unsigned short f2bf(float f) {
  unsigned int u = __builtin_bit_cast(unsigned int, f);
  u += 0x7FFF + ((u >> 16) & 1);              // round-to-nearest-even
  return (unsigned short)(u >> 16);
}
__device__ inline float bf2f(unsigned short h) {
  unsigned int u = ((unsigned int)h) << 16;
  return __builtin_bit_cast(float, u);
}
__device__ inline void gl_lds16(const void* g, void* l) {
  __builtin_amdgcn_global_load_lds(
      (const __attribute__((address_space(1))) unsigned int*)g,
      (__attribute__((address_space(3))) unsigned int*)l, 16, 0, 0);
}
__device__ inline f4 mfma16(bf8 a, bf8 b, f4 c) {
  return __builtin_amdgcn_mfma_f32_16x16x32_bf16(a, b, c, 0, 0, 0);
}
__device__ inline f16v mfma32(bf8 a, bf8 b, f16v c) {
  return __builtin_amdgcn_mfma_f32_32x32x16_bf16(a, b, c, 0, 0, 0);
}
__device__ inline unsigned cvtpk(float lo, float hi) {
  unsigned r;
  asm("v_cvt_pk_bf16_f32 %0, %1, %2" : "=v"(r) : "v"(lo), "v"(hi));
  return r;
}

// ---------------- fused f32 -> bf16 conversion (x, wqkv, wo in one launch) ----------------
__global__ void k_f2bf3(const float* __restrict__ x, const float* __restrict__ wq,
                        const float* __restrict__ wo,
                        unsigned short* __restrict__ xb, unsigned short* __restrict__ wqb,
                        unsigned short* __restrict__ wob) {
  const long n0 = (long)M_TOK * DIM / 4;
  const long n1 = (long)EDIM * DIM / 4;
  const long n2 = (long)DIM * DIM / 4;
  const long total = n0 + n1 + n2;
  const long stride = (long)gridDim.x * blockDim.x;
  for (long i = (long)blockIdx.x * blockDim.x + threadIdx.x; i < total; i += stride) {
    const float* in; unsigned short* out; long j = i;
    if (j < n0)              { in = x;  out = xb; }
    else if ((j -= n0) < n1) { in = wq; out = wqb; }
    else       { j -= n1;      in = wo; out = wob; }
    f4 v = *(const f4*)(in + j * 4);
    unsigned long long pack =
        (unsigned long long)f2bf(v[0]) |
        ((unsigned long long)f2bf(v[1]) << 16) |
        ((unsigned long long)f2bf(v[2]) << 32) |
        ((unsigned long long)f2bf(v[3]) << 48);
    *(unsigned long long*)(out + j * 4) = pack;
  }
}

// =============== GEMM1: 128x384 tiles, 3-phase, SINGLE-BUFFERED LDS (64 KiB) ===============
// R14: identical to R13's schedule, but __launch_bounds__(512, 2).  R13's (512,4)
// made the compiler cap VGPRs at 64 (it budgeted 8 waves/EU for the 8-wave block)
// -> 96-VGPR accumulator spilled to scratch (WRITE_SIZE 49MB -> 1.9GB, 918 us).
// With (512,2) the compiler allocates ~100 VGPR (as R12) and runtime occupancy is
// resource-set: LDS 64 KiB -> 2 blocks/CU; ~100 VGPR <= 128 -> 4 waves/SIMD.
// Ledger (unchanged from R13): prologue[A,B0,B1(0)] vmcnt(2); ph1 stages B2(tc),
// ph1-end vmcnt(2) [B1(tc)]; ph2 stages A,B0(tc+1), ph2-end vmcnt(4) [B2(tc)];
// ph3 stages B1(tc+1), ph3-end vmcnt(2) [A,B0(tc+1)].  Panels die at their phase's
// lgkm0+barrier (frags in regs), so same-slot restaging is race-free.
__global__ __launch_bounds__(512, 2)
void k_gemm384(const unsigned short* __restrict__ A, const unsigned short* __restrict__ Bm,
               unsigned short* __restrict__ oQ, unsigned short* __restrict__ oK,
               unsigned short* __restrict__ oV) {
  __shared__ unsigned short As[8192];
  __shared__ unsigned short Bs[3][8192];
  const int n0 = blockIdx.x;
  const int x = n0 & 7, ix = n0 >> 3;          // ix in [0,64)
  const int bm = ((x >> 1) << 3) + (ix >> 3);  // [0,32)
  const int bn = ((x & 1) << 3) + (ix & 7);    // [0,16)
  const int t = threadIdx.x;
  const int lane = t & 63, w = t >> 6;
  const int wr = w >> 2, wc = w & 3;
  const int l15 = lane & 15, lhi = lane >> 4;
  const int KT = DIM >> 6;                     // 64

  f4 acc[4][6] = {};                           // [mi][bh*2+ni]

  const int tt0 = t * 8;
  auto stA = [&](int tile) {
    if (tile >= KT) return;
    const unsigned short* gp = A + (size_t)(bm * 128) * DIM + tile * 64;
#pragma unroll
    for (int j = 0; j < 2; ++j) {
      int e = j * 4096 + tt0;
      int rl = e >> 6, cs = (e & 63) ^ ((rl & 7) << 3);
      gl_lds16(gp + (size_t)rl * DIM + cs, &As[e]);
    }
  };
  auto stB = [&](int bh, int tile) {
    if (tile >= KT) return;
    const unsigned short* gp = Bm + (size_t)(bn * 384 + bh * 128) * DIM + tile * 64;
#pragma unroll
    for (int j = 0; j < 2; ++j) {
      int e = j * 4096 + tt0;
      int rl = e >> 6, cs = (e & 63) ^ ((rl & 7) << 3);
      gl_lds16(gp + (size_t)rl * DIM + cs, &Bs[bh][e]);
    }
  };
  auto rdA = [&](int mi, int kk) -> bf8 {
    int row = wr * 64 + mi * 16 + l15;
    int col = (lhi * 8 + kk * 32) ^ ((row & 7) << 3);
    return __builtin_bit_cast(bf8, *(const us8*)&As[row * 64 + col]);
  };
  auto rdB = [&](int bh, int ni, int kk) -> bf8 {
    int row = wc * 32 + ni * 16 + l15;
    int col = (lhi * 8 + kk * 32) ^ ((row & 7) << 3);
    return __builtin_bit_cast(bf8, *(const us8*)&Bs[bh][row * 64 + col]);
  };
  auto bar = [&]() {
    asm volatile("" ::: "memory");
    __builtin_amdgcn_s_barrier();
    asm volatile("" ::: "memory");
  };
  auto lgkm0 = [&]() {
    asm volatile("s_waitcnt lgkmcnt(0)" ::: "memory");
    __builtin_amdgcn_sched_barrier(0);
  };

  // prologue: stage A,B0,B1 of tile0 (6 loads); publish A,B0 (leave B1 in flight)
  stA(0); stB(0, 0); stB(1, 0);
  asm volatile("s_waitcnt vmcnt(2)" ::: "memory");
  bar();

  for (int tc = 0; tc < KT; ++tc) {
    const bool last = (tc == KT - 1);
    bf8 af[4][2], bfr[2][2];
    // ---- ph1: stage B2(tc); read A,B0(tc); MFMA b0 ----
    stB(2, tc);
#pragma unroll
    for (int mi = 0; mi < 4; ++mi)
#pragma unroll
      for (int kk = 0; kk < 2; ++kk) af[mi][kk] = rdA(mi, kk);
#pragma unroll
    for (int ni = 0; ni < 2; ++ni)
#pragma unroll
      for (int kk = 0; kk < 2; ++kk) bfr[ni][kk] = rdB(0, ni, kk);
    lgkm0();
    __builtin_amdgcn_s_setprio(1);
#pragma unroll
    for (int mi = 0; mi < 4; ++mi)
#pragma unroll
      for (int ni = 0; ni < 2; ++ni)
#pragma unroll
        for (int kk = 0; kk < 2; ++kk)
          acc[mi][ni] = mfma16(af[mi][kk], bfr[ni][kk], acc[mi][ni]);
    __builtin_amdgcn_s_setprio(0);
    asm volatile("s_waitcnt vmcnt(2)" ::: "memory");   // publish B1(tc)
    bar();
    // ---- ph2: stage A,B0(tc+1); read B1(tc); MFMA b1 ----
    stA(tc + 1); stB(0, tc + 1);
#pragma unroll
    for (int ni = 0; ni < 2; ++ni)
#pragma unroll
      for (int kk = 0; kk < 2; ++kk) bfr[ni][kk] = rdB(1, ni, kk);
    lgkm0();
    __builtin_amdgcn_s_setprio(1);
#pragma unroll
    for (int mi = 0; mi < 4; ++mi)
#pragma unroll
      for (int ni = 0; ni < 2; ++ni)
#pragma unroll
        for (int kk = 0; kk < 2; ++kk)
          acc[mi][2 + ni] = mfma16(af[mi][kk], bfr[ni][kk], acc[mi][2 + ni]);
    __builtin_amdgcn_s_setprio(0);
    if (last) { asm volatile("s_waitcnt vmcnt(0)" ::: "memory"); }
    else      { asm volatile("s_waitcnt vmcnt(4)" ::: "memory"); }   // publish B2(tc)
    bar();
    // ---- ph3: stage B1(tc+1); read B2(tc); MFMA b2 ----
    stB(1, tc + 1);
#pragma unroll
    for (int ni = 0; ni < 2; ++ni)
#pragma unroll
      for (int kk = 0; kk < 2; ++kk) bfr[ni][kk] = rdB(2, ni, kk);
    lgkm0();
    __builtin_amdgcn_s_setprio(1);
#pragma unroll
    for (int mi = 0; mi < 4; ++mi)
#pragma unroll
      for (int ni = 0; ni < 2; ++ni)
#pragma unroll
        for (int kk = 0; kk < 2; ++kk)
          acc[mi][4 + ni] = mfma16(af[mi][kk], bfr[ni][kk], acc[mi][4 + ni]);
    __builtin_amdgcn_s_setprio(0);
    if (!last) {
      asm volatile("s_waitcnt vmcnt(2)" ::: "memory");  // publish A,B0(tc+1)
      bar();
    }
  }

  // epilogue: Q/K/V region per 16-col sub-block (boundaries 4096/5120 are x16)
#pragma unroll
  for (int bh = 0; bh < 3; ++bh)
#pragma unroll
    for (int ni = 0; ni < 2; ++ni) {
      const int colb = bn * 384 + bh * 128 + wc * 32 + ni * 16;
      unsigned short* op; int ldo, c0;
      if (colb < 4096)      { op = oQ; ldo = 4096; c0 = colb; }
      else if (colb < 5120) { op = oK; ldo = 1024; c0 = colb - 4096; }
      else                  { op = oV; ldo = 1024; c0 = colb - 5120; }
#pragma unroll
      for (int mi = 0; mi < 4; ++mi)
#pragma unroll
        for (int rr = 0; rr < 4; ++rr) {
          int row = bm * 128 + wr * 64 + mi * 16 + lhi * 4 + rr;
          op[(size_t)row * ldo + c0 + l15] = f2bf(acc[mi][bh * 2 + ni][rr]);
        }
    }
}

// =============== GEMM2: 256x256 8-phase mfma16, f32 out; single barrier/phase ======
#define MFMA_Q(a0, b0, AF, BF)                                        \
  __builtin_amdgcn_s_setprio(1);                                      \
  _Pragma("unroll") for (int mi = 0; mi < 4; ++mi)                    \
  _Pragma("unroll") for (int ni = 0; ni < 2; ++ni)                    \
  _Pragma("unroll") for (int kk = 0; kk < 2; ++kk)                    \
      acc[(a0) + mi][(b0) + ni] =                                     \
          mfma16(AF[mi][kk], BF[ni][kk], acc[(a0) + mi][(b0) + ni]);  \
  __builtin_amdgcn_s_setprio(0);

#define RD_A(buf, mh)                                                 \
  _Pragma("unroll") for (int mi = 0; mi < 4; ++mi)                    \
  _Pragma("unroll") for (int kk = 0; kk < 2; ++kk)                    \
      af[mi][kk] = rdA(buf, mh, mi, kk);

#define RD_B(buf, nh, BF)                                             \
  _Pragma("unroll") for (int ni = 0; ni < 2; ++ni)                    \
  _Pragma("unroll") for (int kk = 0; kk < 2; ++kk)                    \
      BF[ni][kk] = rdB(buf, nh, ni, kk);

__global__ __launch_bounds__(512, 2)
void k_gemm256f(const unsigned short* __restrict__ A, const unsigned short* __restrict__ Bm,
                float* __restrict__ oF) {
  __shared__ unsigned short As[2][16384];
  __shared__ unsigned short Bs[2][16384];
  // grid 256 = 16bm x 16bn; XCD x owns a 4bm x 8bn chunk (bn fast)
  const int n0 = blockIdx.x;
  const int x = n0 & 7, ix = n0 >> 3;          // ix in [0,32)
  const int bm = ((x >> 1) << 2) + (ix >> 3);  // [0,16)
  const int bn = ((x & 1) << 3) + (ix & 7);    // [0,16)
  const int N = DIM, K = DIM;
  const int t = threadIdx.x;
  const int lane = t & 63, w = t >> 6;
  const int wr = w >> 2, wc = w & 3;
  const int l15 = lane & 15, lhi = lane >> 4;
  const int KT = K >> 6;
  const int NI = KT >> 1;

  f4 acc[8][4] = {};

  const int tt0 = t * 8;
  auto stA = [&](int buf, int half, int tile) {
    if (tile >= KT) return;
    const unsigned short* gp = A + (size_t)(bm * 256 + half * 128) * K + tile * 64;
#pragma unroll
    for (int j = 0; j < 2; ++j) {
      int e = j * 4096 + tt0;
      int rl = e >> 6;
      int cs = (e & 63) ^ ((rl & 7) << 3);
      gl_lds16(gp + (size_t)rl * K + cs, &As[buf][half * 8192 + e]);
    }
  };
  auto stB = [&](int buf, int half, int tile) {
    if (tile >= KT) return;
    const unsigned short* gp = Bm + (size_t)(bn * 256 + half * 128) * K + tile * 64;
#pragma unroll
    for (int j = 0; j < 2; ++j) {
      int e = j * 4096 + tt0;
      int rl = e >> 6;
      int cs = (e & 63) ^ ((rl & 7) << 3);
      gl_lds16(gp + (size_t)rl * K + cs, &Bs[buf][half * 8192 + e]);
    }
  };
  auto rdA = [&](int buf, int mh, int mi, int kk) -> bf8 {
    int row = mh * 128 + wr * 64 + mi * 16 + l15;
    int col = (lhi * 8 + kk * 32) ^ ((row & 7) << 3);
    return __builtin_bit_cast(bf8, *(const us8*)&As[buf][row * 64 + col]);
  };
  auto rdB = [&](int buf, int nh, int ni, int kk) -> bf8 {
    int row = nh * 128 + wc * 32 + ni * 16 + l15;
    int col = (lhi * 8 + kk * 32) ^ ((row & 7) << 3);
    return __builtin_bit_cast(bf8, *(const us8*)&Bs[buf][row * 64 + col]);
  };
  auto bar = [&]() {
    asm volatile("" ::: "memory");
    __builtin_amdgcn_s_barrier();
    asm volatile("" ::: "memory");
  };
  auto lgkm0 = [&]() {
    asm volatile("s_waitcnt lgkmcnt(0)" ::: "memory");
    __builtin_amdgcn_sched_barrier(0);
  };

  stA(0, 0, 0); stB(0, 1, 0); stA(0, 1, 0); stB(0, 0, 0);
  stA(1, 0, 1); stB(1, 1, 1); stA(1, 1, 1);
  asm volatile("s_waitcnt vmcnt(6)" ::: "memory");
  bar();

  for (int i = 0; i < NI; ++i) {
    const int t2 = 2 * i + 2, t3 = 2 * i + 3;
    bf8 af[4][2], bf0[2][2], bf1[2][2];
    // ph1
    RD_A(0, 0); RD_B(0, 0, bf0);
    stB(1, 0, 2 * i + 1);
    lgkm0();
    MFMA_Q(0, 0, af, bf0);
    bar();
    // ph2
    RD_B(0, 1, bf1);
    stA(0, 0, t2);
    lgkm0();
    MFMA_Q(0, 2, af, bf1);
    bar();
    // ph3
    RD_A(0, 1);
    stB(0, 1, t2);
    lgkm0();
    MFMA_Q(4, 2, af, bf1);
    bar();
    // ph4 (bf0 retained from ph1 - no re-read)
    stA(0, 1, t2);
    MFMA_Q(4, 0, af, bf0);
    if (i + 1 < NI) { asm volatile("s_waitcnt vmcnt(6)" ::: "memory"); }
    else            { asm volatile("s_waitcnt vmcnt(0)" ::: "memory"); }
    bar();
    // ph5
    RD_A(1, 0); RD_B(1, 0, bf0);
    stB(0, 0, t2);
    lgkm0();
    MFMA_Q(0, 0, af, bf0);
    bar();
    // ph6
    RD_B(1, 1, bf1);
    stA(1, 0, t3);
    lgkm0();
    MFMA_Q(0, 2, af, bf1);
    bar();
    // ph7
    RD_A(1, 1);
    stB(1, 1, t3);
    lgkm0();
    MFMA_Q(4, 2, af, bf1);
    bar();
    // ph8 (bf0 retained from ph5)
    stA(1, 1, t3);
    MFMA_Q(4, 0, af, bf0);
    if (i + 1 < NI) { asm volatile("s_waitcnt vmcnt(6)" ::: "memory"); }
    bar();
  }

  const int rb0 = bm * 256 + wr * 64 + lhi * 4;
  const int cb0 = bn * 256 + wc * 32 + l15;
#pragma unroll
  for (int ai = 0; ai < 8; ++ai)
#pragma unroll
    for (int bj = 0; bj < 4; ++bj)
#pragma unroll
      for (int rr = 0; rr < 4; ++rr) {
        int row = rb0 + (ai >> 2) * 128 + (ai & 3) * 16 + rr;
        int col = cb0 + (bj >> 1) * 128 + (bj & 1) * 16;
        oF[(size_t)row * N + col] = acc[ai][bj][rr];
      }
}

// ---------------- Flash attention, BALANCED pairs (R12 version) ----------------
__global__ __launch_bounds__(512, 2)
void k_attn(const unsigned short* __restrict__ Qb, const unsigned short* __restrict__ Kb,
            const unsigned short* __restrict__ Vb, unsigned short* __restrict__ Yb,
            const float* __restrict__ cosp, const float* __restrict__ sinp) {
  __shared__ unsigned short Ks[64 * 128];
  __shared__ unsigned short Vt[128 * 64];
  const int idx = blockIdx.x;               // [0,256)
  const int p = idx >> 6;                   // pair index [0,4)
  const int hb = idx & 63;
  const int h = hb >> 1;
  const int b = hb & 1;
  const int kvh = h >> 2;
  const int t = threadIdx.x;
  const int lane = t & 63, w = t >> 6;
  const int l31 = lane & 31, hh = lane >> 5;
  const float BNEG = -1.0e30f;
  const float QSCALE = (float)(0.08838834764831845 * 1.4426950408889634);
  const int swz = (l31 & 7) << 3;           // element-unit XOR swizzle (bits 3..5)
  const int krow = t >> 4;                  // [0,32): K staging row (i=0), +32 (i=1)
  const int kcol = (t & 15) * 8;            // 4 interleaved pairs, 8 contiguous elems

  for (int qq = 0; qq < 2; ++qq) {
    const int qblk = qq ? p : 7 - p;        // heavy tile first
    const int qb0 = qblk * 256;
    const int NT = (qblk + 1) * 4;
    const int wqmin = qb0 + w * 32;
    const int q_g = wqmin + l31;            // this lane's q row (S/P layout)

    // Q fragments, roped in-register
    bf8 qf[8];
    {
      const unsigned short* qp = Qb + (size_t)(b * T_SEQ + q_g) * 4096 + h * 128 + hh * 8;
#pragma unroll
      for (int st = 0; st < 8; ++st) {
        us8 v = *(const us8*)(qp + st * 16);
        f4 c = *(const f4*)(cosp + q_g * 64 + st * 8 + hh * 4);
        f4 s = *(const f4*)(sinp + q_g * 64 + st * 8 + hh * 4);
        us8 o;
#pragma unroll
        for (int j = 0; j < 4; ++j) {
          float tr = bf2f(v[2 * j]), ti = bf2f(v[2 * j + 1]);
          o[2 * j]     = f2bf((tr * c[j] - ti * s[j]) * QSCALE);
          o[2 * j + 1] = f2bf((tr * s[j] + ti * c[j]) * QSCALE);
        }
        qf[st] = __builtin_bit_cast(bf8, o);
      }
    }
    float m_run = BNEG, l_run = 0.f;
    f16v yacc[4] = {};

    for (int kt = 0; kt < NT; ++kt) {
      const int kbase = kt * 64;
      // hoisted global loads (V and K), land during barrier wait
      const unsigned short* vp = Vb + (size_t)(b * T_SEQ + kbase + lane) * 1024 + kvh * 128 + w * 8;
      us8 vv0 = *(const us8*)vp;
      us8 vv1 = *(const us8*)(vp + 64);
      const unsigned short* kp = Kb + (size_t)(b * T_SEQ + kbase + krow) * 1024 + kvh * 128 + kcol;
      us8 kk0 = *(const us8*)kp;
      us8 kk1 = *(const us8*)(kp + (size_t)32 * 1024);
      f4 kc0 = *(const f4*)(cosp + (kbase + krow) * 64 + (kcol >> 1));
      f4 ks0 = *(const f4*)(sinp + (kbase + krow) * 64 + (kcol >> 1));
      f4 kc1 = *(const f4*)(cosp + (kbase + krow + 32) * 64 + (kcol >> 1));
      f4 ks1 = *(const f4*)(sinp + (kbase + krow + 32) * 64 + (kcol >> 1));
      __syncthreads();                      // prev tile's LDS reads done
      // K: rope in-register, write to swizzled LDS
      {
        us8 o0, o1;
#pragma unroll
        for (int j = 0; j < 4; ++j) {
          float tr0 = bf2f(kk0[2 * j]), ti0 = bf2f(kk0[2 * j + 1]);
          o0[2 * j]     = f2bf(tr0 * kc0[j] - ti0 * ks0[j]);
          o0[2 * j + 1] = f2bf(tr0 * ks0[j] + ti0 * kc0[j]);
          float tr1 = bf2f(kk1[2 * j]), ti1 = bf2f(kk1[2 * j + 1]);
          o1[2 * j]     = f2bf(tr1 * kc1[j] - ti1 * ks1[j]);
          o1[2 * j + 1] = f2bf(tr1 * ks1[j] + ti1 * kc1[j]);
        }
        *(us8*)&Ks[krow * 128 + (kcol ^ ((krow & 7) << 3))] = o0;
        *(us8*)&Ks[(krow + 32) * 128 + (kcol ^ ((krow & 7) << 3))] = o1;
      }
      // V: transpose-scatter into swizzled Vt
#pragma unroll
      for (int j = 0; j < 8; ++j) {
        int d0 = w * 8 + j;
        Vt[(d0 * 64 + lane) ^ ((d0 & 7) << 3)] = vv0[j];
        int d1 = d0 + 64;
        Vt[(d1 * 64 + lane) ^ ((d1 & 7) << 3)] = vv1[j];
      }
      __syncthreads();                      // staged data visible
      if (kbase > wqmin + 31) continue;     // tile fully masked for this wave (uniform)

      f16v s0 = {}, s1 = {};
#pragma unroll
      for (int st = 0; st < 8; ++st) {
        int coff = st * 16 + hh * 8;
        bf8 a0 = __builtin_bit_cast(bf8, *(const us8*)&Ks[(l31 * 128 + coff) ^ swz]);
        bf8 a1 = __builtin_bit_cast(bf8, *(const us8*)&Ks[((l31 + 32) * 128 + coff) ^ swz]);
        s0 = mfma32(a0, qf[st], s0);
        s1 = mfma32(a1, qf[st], s1);
      }
      if (kbase + 63 > wqmin) {
#pragma unroll
        for (int r = 0; r < 16; ++r) {
          int kv = kbase + (r & 3) + 8 * (r >> 2) + 4 * hh;
          if (kv > q_g)      s0[r] = BNEG;
          if (kv + 32 > q_g) s1[r] = BNEG;
        }
      }
      float tmax = BNEG;
#pragma unroll
      for (int r = 0; r < 16; ++r) {
        tmax = fmaxf(tmax, s0[r]);
        tmax = fmaxf(tmax, s1[r]);
      }
      tmax = fmaxf(tmax, __shfl_xor(tmax, 32));
      float m_new = fmaxf(m_run, tmax);
      float fac = exp2f(m_run - m_new);     // per q=l31; exact 1.0 when max unchanged
      m_run = m_new;
      float psum = 0.f;
#pragma unroll
      for (int r = 0; r < 16; ++r) {
        s0[r] = exp2f(s0[r] - m_new); psum += s0[r];
        s1[r] = exp2f(s1[r] - m_new); psum += s1[r];
      }
      psum += __shfl_xor(psum, 32);
      l_run = l_run * fac + psum;
      if (!__all(fac == 1.0f)) {
        float facr[16];
#pragma unroll
        for (int r = 0; r < 16; ++r)
          facr[r] = __shfl(fac, (r & 3) + 8 * (r >> 2) + 4 * hh);
#pragma unroll
        for (int dc = 0; dc < 4; ++dc)
#pragma unroll
          for (int r = 0; r < 16; ++r) yacc[dc][r] *= facr[r];
      }
#pragma unroll
      for (int st = 0; st < 4; ++st) {
        f16v sv = (st & 2) ? s1 : s0;
        const int rb = (st & 1) * 8;
        unsigned pkA = cvtpk(sv[rb + 0], sv[rb + 1]);
        unsigned pkB = cvtpk(sv[rb + 2], sv[rb + 3]);
        unsigned pkC = cvtpk(sv[rb + 4], sv[rb + 5]);
        unsigned pkD = cvtpk(sv[rb + 6], sv[rb + 7]);
        unsigned xA = __shfl_xor(pkA, 32);
        unsigned xB = __shfl_xor(pkB, 32);
        unsigned xC = __shfl_xor(pkC, 32);
        unsigned xD = __shfl_xor(pkD, 32);
        unsigned w0 = hh ? xC : pkA;
        unsigned w1 = hh ? xD : pkB;
        unsigned w2 = hh ? pkC : xA;
        unsigned w3 = hh ? pkD : xB;
        i4 wi = { (int)w0, (int)w1, (int)w2, (int)w3 };
        bf8 pf = __builtin_bit_cast(bf8, wi);
#pragma unroll
        for (int dc = 0; dc < 4; ++dc) {
          int d = dc * 32 + l31;
          bf8 vf = __builtin_bit_cast(bf8, *(const us8*)&Vt[(d * 64 + st * 16 + hh * 8) ^ swz]);
          yacc[dc] = mfma32(pf, vf, yacc[dc]);
        }
      }
    }
    float inv_l = 1.0f / l_run;
    float il[16];
#pragma unroll
    for (int r = 0; r < 16; ++r)
      il[r] = __shfl(inv_l, (r & 3) + 8 * (r >> 2) + 4 * hh);
#pragma unroll
    for (int dc = 0; dc < 4; ++dc)
#pragma unroll
      for (int r = 0; r < 16; ++r) {
        int qrow = qb0 + w * 32 + (r & 3) + 8 * (r >> 2) + 4 * hh;
        Yb[(size_t)(b * T_SEQ + qrow) * 4096 + h * 128 + dc * 32 + l31] =
            f2bf(yacc[dc][r] * il[r]);
      }
  }
}

extern "C" void kernel_launch(void* const* d_in, const int* in_sizes, int n_in,
                              void* d_out, int out_size, void* d_ws, size_t ws_size,
                              hipStream_t stream) {
  const float* x    = (const float*)d_in[0];
  // d_in[1] = freqs_cis (unused by the reference computation)
  const float* wqkv = (const float*)d_in[2];
  const float* wo   = (const float*)d_in[3];
  const float* cosp = (const float*)d_in[4];
  const float* sinp = (const float*)d_in[5];
  float* out = (float*)d_out;

  char* ws = (char*)d_ws;
  size_t o = 0;
  auto alloc = [&](size_t bytes) { void* p = ws + o; o += (bytes + 255) & ~(size_t)255; return p; };
  unsigned short* x_b    = (unsigned short*)alloc((size_t)M_TOK * DIM * 2);
  unsigned short* wqkv_b = (unsigned short*)alloc((size_t)EDIM * DIM * 2);
  unsigned short* wo_b   = (unsigned short*)alloc((size_t)DIM * DIM * 2);
  unsigned short* Qb     = (unsigned short*)alloc((size_t)M_TOK * 4096 * 2);
  unsigned short* Kb     = (unsigned short*)alloc((size_t)M_TOK * 1024 * 2);
  unsigned short* Vb     = (unsigned short*)alloc((size_t)M_TOK * 1024 * 2);
  unsigned short* Yb     = (unsigned short*)alloc((size_t)M_TOK * 4096 * 2);
  if (o > ws_size) return;  // workspace too small: fail visibly (zero output)

  k_f2bf3<<<2048, 256, 0, stream>>>(x, wqkv, wo, x_b, wqkv_b, wo_b);

  k_gemm384<<<dim3(512), 512, 0, stream>>>(x_b, wqkv_b, Qb, Kb, Vb);

  k_attn<<<dim3(256, 1, 1), 512, 0, stream>>>(Qb, Kb, Vb, Yb, cosp, sinp);

  k_gemm256f<<<dim3(256), 512, 0, stream>>>(Yb, wo_b, out);
}

// Round 15
// 510.673 us; speedup vs baseline: 2.4028x; 1.0219x over previous
//
#include <hip/hip_runtime.h>

#define T_SEQ 2048
#define NB    2
#define NH    32
#define NKV   8
#define HD    128
#define DIM   4096
#define EDIM  6144
#define M_TOK 4096   // NB*T_SEQ

typedef __bf16          bf8  __attribute__((ext_vector_type(8)));
typedef unsigned short  us8  __attribute__((ext_vector_type(8)));
typedef float           f4   __attribute__((ext_vector_type(4)));
typedef float           f16v __attribute__((ext_vector_type(16)));
typedef int             i4   __attribute__((ext_vector_type(4)));

__device__ inline unsigned short f2bf(float f) {
  unsigned int u = __builtin_bit_cast(unsigned int, f);
  u += 0x7FFF + ((u >> 16) & 1);              // round-to-nearest-even
  return (unsigned short)(u >> 16);
}
__device__ inline float bf2f(unsigned short h) {
  unsigned int u = ((unsigned int)h) << 16;
  return __builtin_bit_cast(float, u);
}
__device__ inline void gl_lds16(const void* g, void* l) {
  __builtin_amdgcn_global_load_lds(
      (const __attribute__((address_space(1))) unsigned int*)g,
      (__attribute__((address_space(3))) unsigned int*)l, 16, 0, 0);
}
__device__ inline f4 mfma16(bf8 a, bf8 b, f4 c) {
  return __builtin_amdgcn_mfma_f32_16x16x32_bf16(a, b, c, 0, 0, 0);
}
__device__ inline f16v mfma32(bf8 a, bf8 b, f16v c) {
  return __builtin_amdgcn_mfma_f32_32x32x16_bf16(a, b, c, 0, 0, 0);
}
__device__ inline unsigned cvtpk(float lo, float hi) {
  unsigned r;
  asm("v_cvt_pk_bf16_f32 %0, %1, %2" : "=v"(r) : "v"(lo), "v"(hi));
  return r;
}

// ---------------- fused f32 -> bf16 conversion (x, wqkv, wo in one launch) ----------------
__global__ void k_f2bf3(const float* __restrict__ x, const float* __restrict__ wq,
                        const float* __restrict__ wo,
                        unsigned short* __restrict__ xb, unsigned short* __restrict__ wqb,
                        unsigned short* __restrict__ wob) {
  const long n0 = (long)M_TOK * DIM / 4;
  const long n1 = (long)EDIM * DIM / 4;
  const long n2 = (long)DIM * DIM / 4;
  const long total = n0 + n1 + n2;
  const long stride = (long)gridDim.x * blockDim.x;
  for (long i = (long)blockIdx.x * blockDim.x + threadIdx.x; i < total; i += stride) {
    const float* in; unsigned short* out; long j = i;
    if (j < n0)              { in = x;  out = xb; }
    else if ((j -= n0) < n1) { in = wq; out = wqb; }
    else       { j -= n1;      in = wo; out = wob; }
    f4 v = *(const f4*)(in + j * 4);
    unsigned long long pack =
        (unsigned long long)f2bf(v[0]) |
        ((unsigned long long)f2bf(v[1]) << 16) |
        ((unsigned long long)f2bf(v[2]) << 32) |
        ((unsigned long long)f2bf(v[3]) << 48);
    *(unsigned long long*)(out + j * 4) = pack;
  }
}

// =============== GEMM1: 128x384 tiles, 3-phase, double-buffered (R9/R12 best) ===============
// Measured best: 213.8 us, MfmaUtil 42.7%, 0 bank conflicts, no spill.
// 2D XCD chunking; single barrier per phase; counted-vmcnt publish ledger:
// ph1-end vm(6), ph2-end vm(6), ph3-end vm(4); last tile 2/0/skip.
__global__ __launch_bounds__(512, 2)
void k_gemm384(const unsigned short* __restrict__ A, const unsigned short* __restrict__ Bm,
               unsigned short* __restrict__ oQ, unsigned short* __restrict__ oK,
               unsigned short* __restrict__ oV) {
  __shared__ unsigned short As[2][8192];
  __shared__ unsigned short Bs[2][3][8192];
  const int n0 = blockIdx.x;
  const int x = n0 & 7, ix = n0 >> 3;          // ix in [0,64)
  const int bm = ((x >> 1) << 3) + (ix >> 3);  // [0,32)
  const int bn = ((x & 1) << 3) + (ix & 7);    // [0,16)
  const int t = threadIdx.x;
  const int lane = t & 63, w = t >> 6;
  const int wr = w >> 2, wc = w & 3;
  const int l15 = lane & 15, lhi = lane >> 4;
  const int KT = DIM >> 6;                     // 64

  f4 acc[4][6] = {};                           // [mi][bh*2+ni]

  const int tt0 = t * 8;
  auto stA = [&](int buf, int tile) {
    if (tile >= KT) return;
    const unsigned short* gp = A + (size_t)(bm * 128) * DIM + tile * 64;
#pragma unroll
    for (int j = 0; j < 2; ++j) {
      int e = j * 4096 + tt0;
      int rl = e >> 6, cs = (e & 63) ^ ((rl & 7) << 3);
      gl_lds16(gp + (size_t)rl * DIM + cs, &As[buf][e]);
    }
  };
  auto stB = [&](int buf, int bh, int tile) {
    if (tile >= KT) return;
    const unsigned short* gp = Bm + (size_t)(bn * 384 + bh * 128) * DIM + tile * 64;
#pragma unroll
    for (int j = 0; j < 2; ++j) {
      int e = j * 4096 + tt0;
      int rl = e >> 6, cs = (e & 63) ^ ((rl & 7) << 3);
      gl_lds16(gp + (size_t)rl * DIM + cs, &Bs[buf][bh][e]);
    }
  };
  auto rdA = [&](int buf, int mi, int kk) -> bf8 {
    int row = wr * 64 + mi * 16 + l15;
    int col = (lhi * 8 + kk * 32) ^ ((row & 7) << 3);
    return __builtin_bit_cast(bf8, *(const us8*)&As[buf][row * 64 + col]);
  };
  auto rdB = [&](int buf, int bh, int ni, int kk) -> bf8 {
    int row = wc * 32 + ni * 16 + l15;
    int col = (lhi * 8 + kk * 32) ^ ((row & 7) << 3);
    return __builtin_bit_cast(bf8, *(const us8*)&Bs[buf][bh][row * 64 + col]);
  };
  auto bar = [&]() {
    asm volatile("" ::: "memory");
    __builtin_amdgcn_s_barrier();
    asm volatile("" ::: "memory");
  };
  auto lgkm0 = [&]() {
    asm volatile("s_waitcnt lgkmcnt(0)" ::: "memory");
    __builtin_amdgcn_sched_barrier(0);
  };

  // prologue: tile0's 4 panels (8 loads); need A(0),B0(0) before ph1
  stA(0, 0); stB(0, 0, 0); stB(0, 1, 0); stB(0, 2, 0);
  asm volatile("s_waitcnt vmcnt(4)" ::: "memory");
  bar();

  for (int tp = 0; tp < KT; tp += 2) {
#pragma unroll
    for (int sub = 0; sub < 2; ++sub) {
      const int tc = tp + sub, b = sub;
      const bool last = (tc == KT - 1);
      bf8 af[4][2], bfr[2][2];
      // ---- ph1: bh0 ----
#pragma unroll
      for (int mi = 0; mi < 4; ++mi)
#pragma unroll
        for (int kk = 0; kk < 2; ++kk) af[mi][kk] = rdA(b, mi, kk);
#pragma unroll
      for (int ni = 0; ni < 2; ++ni)
#pragma unroll
        for (int kk = 0; kk < 2; ++kk) bfr[ni][kk] = rdB(b, 0, ni, kk);
      stA(b ^ 1, tc + 1); stB(b ^ 1, 0, tc + 1);
      lgkm0();
      __builtin_amdgcn_s_setprio(1);
#pragma unroll
      for (int mi = 0; mi < 4; ++mi)
#pragma unroll
        for (int ni = 0; ni < 2; ++ni)
#pragma unroll
          for (int kk = 0; kk < 2; ++kk)
            acc[mi][ni] = mfma16(af[mi][kk], bfr[ni][kk], acc[mi][ni]);
      __builtin_amdgcn_s_setprio(0);
      if (last) { asm volatile("s_waitcnt vmcnt(2)" ::: "memory"); }
      else      { asm volatile("s_waitcnt vmcnt(6)" ::: "memory"); }
      bar();
      // ---- ph2: bh1 ----
#pragma unroll
      for (int ni = 0; ni < 2; ++ni)
#pragma unroll
        for (int kk = 0; kk < 2; ++kk) bfr[ni][kk] = rdB(b, 1, ni, kk);
      stB(b ^ 1, 1, tc + 1);
      lgkm0();
      __builtin_amdgcn_s_setprio(1);
#pragma unroll
      for (int mi = 0; mi < 4; ++mi)
#pragma unroll
        for (int ni = 0; ni < 2; ++ni)
#pragma unroll
          for (int kk = 0; kk < 2; ++kk)
            acc[mi][2 + ni] = mfma16(af[mi][kk], bfr[ni][kk], acc[mi][2 + ni]);
      __builtin_amdgcn_s_setprio(0);
      if (last) { asm volatile("s_waitcnt vmcnt(0)" ::: "memory"); }
      else      { asm volatile("s_waitcnt vmcnt(6)" ::: "memory"); }
      bar();
      // ---- ph3: bh2 ----
#pragma unroll
      for (int ni = 0; ni < 2; ++ni)
#pragma unroll
        for (int kk = 0; kk < 2; ++kk) bfr[ni][kk] = rdB(b, 2, ni, kk);
      stB(b ^ 1, 2, tc + 1);
      lgkm0();
      __builtin_amdgcn_s_setprio(1);
#pragma unroll
      for (int mi = 0; mi < 4; ++mi)
#pragma unroll
        for (int ni = 0; ni < 2; ++ni)
#pragma unroll
          for (int kk = 0; kk < 2; ++kk)
            acc[mi][4 + ni] = mfma16(af[mi][kk], bfr[ni][kk], acc[mi][4 + ni]);
      __builtin_amdgcn_s_setprio(0);
      if (!last) { asm volatile("s_waitcnt vmcnt(4)" ::: "memory"); }
      bar();
    }
  }

  // epilogue: Q/K/V region per 16-col sub-block (boundaries 4096/5120 are x16)
#pragma unroll
  for (int bh = 0; bh < 3; ++bh)
#pragma unroll
    for (int ni = 0; ni < 2; ++ni) {
      const int colb = bn * 384 + bh * 128 + wc * 32 + ni * 16;
      unsigned short* op; int ldo, c0;
      if (colb < 4096)      { op = oQ; ldo = 4096; c0 = colb; }
      else if (colb < 5120) { op = oK; ldo = 1024; c0 = colb - 4096; }
      else                  { op = oV; ldo = 1024; c0 = colb - 5120; }
#pragma unroll
      for (int mi = 0; mi < 4; ++mi)
#pragma unroll
        for (int rr = 0; rr < 4; ++rr) {
          int row = bm * 128 + wr * 64 + mi * 16 + lhi * 4 + rr;
          op[(size_t)row * ldo + c0 + l15] = f2bf(acc[mi][bh * 2 + ni][rr]);
        }
    }
}

// =============== GEMM2: 256x256 8-phase mfma16, f32 out; single barrier/phase ======
#define MFMA_Q(a0, b0, AF, BF)                                        \
  __builtin_amdgcn_s_setprio(1);                                      \
  _Pragma("unroll") for (int mi = 0; mi < 4; ++mi)                    \
  _Pragma("unroll") for (int ni = 0; ni < 2; ++ni)                    \
  _Pragma("unroll") for (int kk = 0; kk < 2; ++kk)                    \
      acc[(a0) + mi][(b0) + ni] =                                     \
          mfma16(AF[mi][kk], BF[ni][kk], acc[(a0) + mi][(b0) + ni]);  \
  __builtin_amdgcn_s_setprio(0);

#define RD_A(buf, mh)                                                 \
  _Pragma("unroll") for (int mi = 0; mi < 4; ++mi)                    \
  _Pragma("unroll") for (int kk = 0; kk < 2; ++kk)                    \
      af[mi][kk] = rdA(buf, mh, mi, kk);

#define RD_B(buf, nh, BF)                                             \
  _Pragma("unroll") for (int ni = 0; ni < 2; ++ni)                    \
  _Pragma("unroll") for (int kk = 0; kk < 2; ++kk)                    \
      BF[ni][kk] = rdB(buf, nh, ni, kk);

__global__ __launch_bounds__(512, 2)
void k_gemm256f(const unsigned short* __restrict__ A, const unsigned short* __restrict__ Bm,
                float* __restrict__ oF) {
  __shared__ unsigned short As[2][16384];
  __shared__ unsigned short Bs[2][16384];
  // grid 256 = 16bm x 16bn; XCD x owns a 4bm x 8bn chunk (bn fast)
  const int n0 = blockIdx.x;
  const int x = n0 & 7, ix = n0 >> 3;          // ix in [0,32)
  const int bm = ((x >> 1) << 2) + (ix >> 3);  // [0,16)
  const int bn = ((x & 1) << 3) + (ix & 7);    // [0,16)
  const int N = DIM, K = DIM;
  const int t = threadIdx.x;
  const int lane = t & 63, w = t >> 6;
  const int wr = w >> 2, wc = w & 3;
  const int l15 = lane & 15, lhi = lane >> 4;
  const int KT = K >> 6;
  const int NI = KT >> 1;

  f4 acc[8][4] = {};

  const int tt0 = t * 8;
  auto stA = [&](int buf, int half, int tile) {
    if (tile >= KT) return;
    const unsigned short* gp = A + (size_t)(bm * 256 + half * 128) * K + tile * 64;
#pragma unroll
    for (int j = 0; j < 2; ++j) {
      int e = j * 4096 + tt0;
      int rl = e >> 6;
      int cs = (e & 63) ^ ((rl & 7) << 3);
      gl_lds16(gp + (size_t)rl * K + cs, &As[buf][half * 8192 + e]);
    }
  };
  auto stB = [&](int buf, int half, int tile) {
    if (tile >= KT) return;
    const unsigned short* gp = Bm + (size_t)(bn * 256 + half * 128) * K + tile * 64;
#pragma unroll
    for (int j = 0; j < 2; ++j) {
      int e = j * 4096 + tt0;
      int rl = e >> 6;
      int cs = (e & 63) ^ ((rl & 7) << 3);
      gl_lds16(gp + (size_t)rl * K + cs, &Bs[buf][half * 8192 + e]);
    }
  };
  auto rdA = [&](int buf, int mh, int mi, int kk) -> bf8 {
    int row = mh * 128 + wr * 64 + mi * 16 + l15;
    int col = (lhi * 8 + kk * 32) ^ ((row & 7) << 3);
    return __builtin_bit_cast(bf8, *(const us8*)&As[buf][row * 64 + col]);
  };
  auto rdB = [&](int buf, int nh, int ni, int kk) -> bf8 {
    int row = nh * 128 + wc * 32 + ni * 16 + l15;
    int col = (lhi * 8 + kk * 32) ^ ((row & 7) << 3);
    return __builtin_bit_cast(bf8, *(const us8*)&Bs[buf][row * 64 + col]);
  };
  auto bar = [&]() {
    asm volatile("" ::: "memory");
    __builtin_amdgcn_s_barrier();
    asm volatile("" ::: "memory");
  };
  auto lgkm0 = [&]() {
    asm volatile("s_waitcnt lgkmcnt(0)" ::: "memory");
    __builtin_amdgcn_sched_barrier(0);
  };

  stA(0, 0, 0); stB(0, 1, 0); stA(0, 1, 0); stB(0, 0, 0);
  stA(1, 0, 1); stB(1, 1, 1); stA(1, 1, 1);
  asm volatile("s_waitcnt vmcnt(6)" ::: "memory");
  bar();

  for (int i = 0; i < NI; ++i) {
    const int t2 = 2 * i + 2, t3 = 2 * i + 3;
    bf8 af[4][2], bf0[2][2], bf1[2][2];
    // ph1
    RD_A(0, 0); RD_B(0, 0, bf0);
    stB(1, 0, 2 * i + 1);
    lgkm0();
    MFMA_Q(0, 0, af, bf0);
    bar();
    // ph2
    RD_B(0, 1, bf1);
    stA(0, 0, t2);
    lgkm0();
    MFMA_Q(0, 2, af, bf1);
    bar();
    // ph3
    RD_A(0, 1);
    stB(0, 1, t2);
    lgkm0();
    MFMA_Q(4, 2, af, bf1);
    bar();
    // ph4 (bf0 retained from ph1 - no re-read)
    stA(0, 1, t2);
    MFMA_Q(4, 0, af, bf0);
    if (i + 1 < NI) { asm volatile("s_waitcnt vmcnt(6)" ::: "memory"); }
    else            { asm volatile("s_waitcnt vmcnt(0)" ::: "memory"); }
    bar();
    // ph5
    RD_A(1, 0); RD_B(1, 0, bf0);
    stB(0, 0, t2);
    lgkm0();
    MFMA_Q(0, 0, af, bf0);
    bar();
    // ph6
    RD_B(1, 1, bf1);
    stA(1, 0, t3);
    lgkm0();
    MFMA_Q(0, 2, af, bf1);
    bar();
    // ph7
    RD_A(1, 1);
    stB(1, 1, t3);
    lgkm0();
    MFMA_Q(4, 2, af, bf1);
    bar();
    // ph8 (bf0 retained from ph5)
    stA(1, 1, t3);
    MFMA_Q(4, 0, af, bf0);
    if (i + 1 < NI) { asm volatile("s_waitcnt vmcnt(6)" ::: "memory"); }
    bar();
  }

  const int rb0 = bm * 256 + wr * 64 + lhi * 4;
  const int cb0 = bn * 256 + wc * 32 + l15;
#pragma unroll
  for (int ai = 0; ai < 8; ++ai)
#pragma unroll
    for (int bj = 0; bj < 4; ++bj)
#pragma unroll
      for (int rr = 0; rr < 4; ++rr) {
        int row = rb0 + (ai >> 2) * 128 + (ai & 3) * 16 + rr;
        int col = cb0 + (bj >> 1) * 128 + (bj & 1) * 16;
        oF[(size_t)row * N + col] = acc[ai][bj][rr];
      }
}

// ---------------- Flash attention, BALANCED pairs (R12 version) ----------------
__global__ __launch_bounds__(512, 2)
void k_attn(const unsigned short* __restrict__ Qb, const unsigned short* __restrict__ Kb,
            const unsigned short* __restrict__ Vb, unsigned short* __restrict__ Yb,
            const float* __restrict__ cosp, const float* __restrict__ sinp) {
  __shared__ unsigned short Ks[64 * 128];
  __shared__ unsigned short Vt[128 * 64];
  const int idx = blockIdx.x;               // [0,256)
  const int p = idx >> 6;                   // pair index [0,4)
  const int hb = idx & 63;
  const int h = hb >> 1;
  const int b = hb & 1;
  const int kvh = h >> 2;
  const int t = threadIdx.x;
  const int lane = t & 63, w = t >> 6;
  const int l31 = lane & 31, hh = lane >> 5;
  const float BNEG = -1.0e30f;
  const float QSCALE = (float)(0.08838834764831845 * 1.4426950408889634);
  const int swz = (l31 & 7) << 3;           // element-unit XOR swizzle (bits 3..5)
  const int krow = t >> 4;                  // [0,32): K staging row (i=0), +32 (i=1)
  const int kcol = (t & 15) * 8;            // 4 interleaved pairs, 8 contiguous elems

  for (int qq = 0; qq < 2; ++qq) {
    const int qblk = qq ? p : 7 - p;        // heavy tile first
    const int qb0 = qblk * 256;
    const int NT = (qblk + 1) * 4;
    const int wqmin = qb0 + w * 32;
    const int q_g = wqmin + l31;            // this lane's q row (S/P layout)

    // Q fragments, roped in-register
    bf8 qf[8];
    {
      const unsigned short* qp = Qb + (size_t)(b * T_SEQ + q_g) * 4096 + h * 128 + hh * 8;
#pragma unroll
      for (int st = 0; st < 8; ++st) {
        us8 v = *(const us8*)(qp + st * 16);
        f4 c = *(const f4*)(cosp + q_g * 64 + st * 8 + hh * 4);
        f4 s = *(const f4*)(sinp + q_g * 64 + st * 8 + hh * 4);
        us8 o;
#pragma unroll
        for (int j = 0; j < 4; ++j) {
          float tr = bf2f(v[2 * j]), ti = bf2f(v[2 * j + 1]);
          o[2 * j]     = f2bf((tr * c[j] - ti * s[j]) * QSCALE);
          o[2 * j + 1] = f2bf((tr * s[j] + ti * c[j]) * QSCALE);
        }
        qf[st] = __builtin_bit_cast(bf8, o);
      }
    }
    float m_run = BNEG, l_run = 0.f;
    f16v yacc[4] = {};

    for (int kt = 0; kt < NT; ++kt) {
      const int kbase = kt * 64;
      // hoisted global loads (V and K), land during barrier wait
      const unsigned short* vp = Vb + (size_t)(b * T_SEQ + kbase + lane) * 1024 + kvh * 128 + w * 8;
      us8 vv0 = *(const us8*)vp;
      us8 vv1 = *(const us8*)(vp + 64);
      const unsigned short* kp = Kb + (size_t)(b * T_SEQ + kbase + krow) * 1024 + kvh * 128 + kcol;
      us8 kk0 = *(const us8*)kp;
      us8 kk1 = *(const us8*)(kp + (size_t)32 * 1024);
      f4 kc0 = *(const f4*)(cosp + (kbase + krow) * 64 + (kcol >> 1));
      f4 ks0 = *(const f4*)(sinp + (kbase + krow) * 64 + (kcol >> 1));
      f4 kc1 = *(const f4*)(cosp + (kbase + krow + 32) * 64 + (kcol >> 1));
      f4 ks1 = *(const f4*)(sinp + (kbase + krow + 32) * 64 + (kcol >> 1));
      __syncthreads();                      // prev tile's LDS reads done
      // K: rope in-register, write to swizzled LDS
      {
        us8 o0, o1;
#pragma unroll
        for (int j = 0; j < 4; ++j) {
          float tr0 = bf2f(kk0[2 * j]), ti0 = bf2f(kk0[2 * j + 1]);
          o0[2 * j]     = f2bf(tr0 * kc0[j] - ti0 * ks0[j]);
          o0[2 * j + 1] = f2bf(tr0 * ks0[j] + ti0 * kc0[j]);
          float tr1 = bf2f(kk1[2 * j]), ti1 = bf2f(kk1[2 * j + 1]);
          o1[2 * j]     = f2bf(tr1 * kc1[j] - ti1 * ks1[j]);
          o1[2 * j + 1] = f2bf(tr1 * ks1[j] + ti1 * kc1[j]);
        }
        *(us8*)&Ks[krow * 128 + (kcol ^ ((krow & 7) << 3))] = o0;
        *(us8*)&Ks[(krow + 32) * 128 + (kcol ^ ((krow & 7) << 3))] = o1;
      }
      // V: transpose-scatter into swizzled Vt
#pragma unroll
      for (int j = 0; j < 8; ++j) {
        int d0 = w * 8 + j;
        Vt[(d0 * 64 + lane) ^ ((d0 & 7) << 3)] = vv0[j];
        int d1 = d0 + 64;
        Vt[(d1 * 64 + lane) ^ ((d1 & 7) << 3)] = vv1[j];
      }
      __syncthreads();                      // staged data visible
      if (kbase > wqmin + 31) continue;     // tile fully masked for this wave (uniform)

      f16v s0 = {}, s1 = {};
#pragma unroll
      for (int st = 0; st < 8; ++st) {
        int coff = st * 16 + hh * 8;
        bf8 a0 = __builtin_bit_cast(bf8, *(const us8*)&Ks[(l31 * 128 + coff) ^ swz]);
        bf8 a1 = __builtin_bit_cast(bf8, *(const us8*)&Ks[((l31 + 32) * 128 + coff) ^ swz]);
        s0 = mfma32(a0, qf[st], s0);
        s1 = mfma32(a1, qf[st], s1);
      }
      if (kbase + 63 > wqmin) {
#pragma unroll
        for (int r = 0; r < 16; ++r) {
          int kv = kbase + (r & 3) + 8 * (r >> 2) + 4 * hh;
          if (kv > q_g)      s0[r] = BNEG;
          if (kv + 32 > q_g) s1[r] = BNEG;
        }
      }
      float tmax = BNEG;
#pragma unroll
      for (int r = 0; r < 16; ++r) {
        tmax = fmaxf(tmax, s0[r]);
        tmax = fmaxf(tmax, s1[r]);
      }
      tmax = fmaxf(tmax, __shfl_xor(tmax, 32));
      float m_new = fmaxf(m_run, tmax);
      float fac = exp2f(m_run - m_new);     // per q=l31; exact 1.0 when max unchanged
      m_run = m_new;
      float psum = 0.f;
#pragma unroll
      for (int r = 0; r < 16; ++r) {
        s0[r] = exp2f(s0[r] - m_new); psum += s0[r];
        s1[r] = exp2f(s1[r] - m_new); psum += s1[r];
      }
      psum += __shfl_xor(psum, 32);
      l_run = l_run * fac + psum;
      if (!__all(fac == 1.0f)) {
        float facr[16];
#pragma unroll
        for (int r = 0; r < 16; ++r)
          facr[r] = __shfl(fac, (r & 3) + 8 * (r >> 2) + 4 * hh);
#pragma unroll
        for (int dc = 0; dc < 4; ++dc)
#pragma unroll
          for (int r = 0; r < 16; ++r) yacc[dc][r] *= facr[r];
      }
#pragma unroll
      for (int st = 0; st < 4; ++st) {
        f16v sv = (st & 2) ? s1 : s0;
        const int rb = (st & 1) * 8;
        unsigned pkA = cvtpk(sv[rb + 0], sv[rb + 1]);
        unsigned pkB = cvtpk(sv[rb + 2], sv[rb + 3]);
        unsigned pkC = cvtpk(sv[rb + 4], sv[rb + 5]);
        unsigned pkD = cvtpk(sv[rb + 6], sv[rb + 7]);
        unsigned xA = __shfl_xor(pkA, 32);
        unsigned xB = __shfl_xor(pkB, 32);
        unsigned xC = __shfl_xor(pkC, 32);
        unsigned xD = __shfl_xor(pkD, 32);
        unsigned w0 = hh ? xC : pkA;
        unsigned w1 = hh ? xD : pkB;
        unsigned w2 = hh ? pkC : xA;
        unsigned w3 = hh ? pkD : xB;
        i4 wi = { (int)w0, (int)w1, (int)w2, (int)w3 };
        bf8 pf = __builtin_bit_cast(bf8, wi);
#pragma unroll
        for (int dc = 0; dc < 4; ++dc) {
          int d = dc * 32 + l31;
          bf8 vf = __builtin_bit_cast(bf8, *(const us8*)&Vt[(d * 64 + st * 16 + hh * 8) ^ swz]);
          yacc[dc] = mfma32(pf, vf, yacc[dc]);
        }
      }
    }
    float inv_l = 1.0f / l_run;
    float il[16];
#pragma unroll
    for (int r = 0; r < 16; ++r)
      il[r] = __shfl(inv_l, (r & 3) + 8 * (r >> 2) + 4 * hh);
#pragma unroll
    for (int dc = 0; dc < 4; ++dc)
#pragma unroll
      for (int r = 0; r < 16; ++r) {
        int qrow = qb0 + w * 32 + (r & 3) + 8 * (r >> 2) + 4 * hh;
        Yb[(size_t)(b * T_SEQ + qrow) * 4096 + h * 128 + dc * 32 + l31] =
            f2bf(yacc[dc][r] * il[r]);
      }
  }
}

extern "C" void kernel_launch(void* const* d_in, const int* in_sizes, int n_in,
                              void* d_out, int out_size, void* d_ws, size_t ws_size,
                              hipStream_t stream) {
  const float* x    = (const float*)d_in[0];
  // d_in[1] = freqs_cis (unused by the reference computation)
  const float* wqkv = (const float*)d_in[2];
  const float* wo   = (const float*)d_in[3];
  const float* cosp = (const float*)d_in[4];
  const float* sinp = (const float*)d_in[5];
  float* out = (float*)d_out;

  char* ws = (char*)d_ws;
  size_t o = 0;
  auto alloc = [&](size_t bytes) { void* p = ws + o; o += (bytes + 255) & ~(size_t)255; return p; };
  unsigned short* x_b    = (unsigned short*)alloc((size_t)M_TOK * DIM * 2);
  unsigned short* wqkv_b = (unsigned short*)alloc((size_t)EDIM * DIM * 2);
  unsigned short* wo_b   = (unsigned short*)alloc((size_t)DIM * DIM * 2);
  unsigned short* Qb     = (unsigned short*)alloc((size_t)M_TOK * 4096 * 2);
  unsigned short* Kb     = (unsigned short*)alloc((size_t)M_TOK * 1024 * 2);
  unsigned short* Vb     = (unsigned short*)alloc((size_t)M_TOK * 1024 * 2);
  unsigned short* Yb     = (unsigned short*)alloc((size_t)M_TOK * 4096 * 2);
  if (o > ws_size) return;  // workspace too small: fail visibly (zero output)

  k_f2bf3<<<2048, 256, 0, stream>>>(x, wqkv, wo, x_b, wqkv_b, wo_b);

  k_gemm384<<<dim3(512), 512, 0, stream>>>(x_b, wqkv_b, Qb, Kb, Vb);

  k_attn<<<dim3(256, 1, 1), 512, 0, stream>>>(Qb, Kb, Vb, Yb, cosp, sinp);

  k_gemm256f<<<dim3(256), 512, 0, stream>>>(Yb, wo_b, out);
}